// Round 9
// baseline (365.293 us; speedup 1.0000x reference)
//
#include <hip/hip_runtime.h>
#include <math.h>

#define N_TOK 8192
#define DMODEL 1024
#define DHEAD 128
#define NM (N_TOK * DHEAD)       // 1048576
#define CS 4                     // column splits for attention passes
#define CCHUNK (N_TOK / CS)      // 2048
#define NIT (CCHUNK / 64)        // 32
#define QSCALE 0.08838834764831845f

typedef __bf16 bf16x8 __attribute__((ext_vector_type(8)));
typedef float f32x4 __attribute__((ext_vector_type(4)));
typedef unsigned short u16;
typedef unsigned int u32;

union B8 { uint4 u; bf16x8 b; };

static __device__ __forceinline__ float4 ld4(const float* p) {
    return *(const float4*)p;
}

static __device__ __forceinline__ void gl_lds16(const void* g, void* l) {
    __builtin_amdgcn_global_load_lds(
        (const __attribute__((address_space(1))) u32*)g,
        (__attribute__((address_space(3))) u32*)l, 16, 0, 0);
}

static __device__ __forceinline__ u16 bfbits(float x) {
    return __builtin_bit_cast(u16, (__bf16)x);
}
static __device__ __forceinline__ u16 b2u(__bf16 h) {
    return __builtin_bit_cast(u16, h);
}

// ---------------------------------------------------------------------------
// K0a: split X fp32 -> Xh, Xl bf16. 8M elements, grid 4096 x 256.
// ---------------------------------------------------------------------------
__global__ __launch_bounds__(256) void split_x(
    const float* __restrict__ X, u16* __restrict__ Xh, u16* __restrict__ Xl) {
    size_t i0 = ((size_t)blockIdx.x * 256 + threadIdx.x) * 8;
    alignas(16) float v[8];
    alignas(16) u16 h[8];
    alignas(16) u16 l[8];
    *(float4*)&v[0] = ld4(X + i0); *(float4*)&v[4] = ld4(X + i0 + 4);
#pragma unroll
    for (int j = 0; j < 8; ++j) {
        __bf16 hb = (__bf16)v[j];
        h[j] = b2u(hb);
        l[j] = bfbits(v[j] - (float)hb);
    }
    *(uint4*)(Xh + i0) = *(uint4*)h;
    *(uint4*)(Xl + i0) = *(uint4*)l;
}

// ---------------------------------------------------------------------------
// K0b: W [1024][128] x3 -> Wt hi/lo [384][1024] (transposed, concat Q|K|V).
// ---------------------------------------------------------------------------
__global__ __launch_bounds__(256) void splitw(
    const float* __restrict__ Wq, const float* __restrict__ Wk,
    const float* __restrict__ Wv, u16* __restrict__ Wth, u16* __restrict__ Wtl) {
    size_t o = (size_t)blockIdx.x * 256 + threadIdx.x;   // 0..393215
    int k = o & 1023, cg = o >> 10;                      // cg 0..383
    int w = cg >> 7, c = cg & 127;
    const float* W = w == 0 ? Wq : (w == 1 ? Wk : Wv);
    float x = W[(size_t)k * 128 + c];
    __bf16 hb = (__bf16)x;
    Wth[o] = b2u(hb);
    Wtl[o] = bfbits(x - (float)hb);
}

// ---------------------------------------------------------------------------
// K1: projections via bf16x3 MFMA, swapped operands (unchanged — fast).
// ---------------------------------------------------------------------------
__global__ __launch_bounds__(256) void proj_mfma(
    const u16* __restrict__ Xh, const u16* __restrict__ Xl,
    const u16* __restrict__ Wth, const u16* __restrict__ Wtl,
    u16* __restrict__ Qh, u16* __restrict__ Ql,
    u16* __restrict__ Kh, u16* __restrict__ Kl, u16* __restrict__ Vt) {
    __shared__ uint4 Xs[2][2][128];   // [buf][hi/lo][r*4 + swizzled granule]
    const int tid = threadIdx.x, lane = tid & 63, wv = tid >> 6;
    const int l15 = lane & 15, lg = lane >> 4;
    const int rb = blockIdx.x * 32;
    const int ch = blockIdx.y;        // c-base = ch*192
    const int rt = wv & 1;            // r-tile (16 rows)
    const int cq = wv >> 1;           // c-quarter (96 cols)

    f32x4 acc[6];
#pragma unroll
    for (int mt = 0; mt < 6; ++mt) acc[mt] = (f32x4){0.f, 0.f, 0.f, 0.f};

    auto stage = [&](int buf, int k0) {
        int split = wv >> 1;
        int idx = (wv & 1) * 64 + lane;     // granule 0..127 within split
        int r = idx >> 2, gs = idx & 3, gd = gs ^ (r & 3);
        const u16* src = (split ? Xl : Xh) +
                         (size_t)(rb + r) * DMODEL + k0 + gd * 8;
        gl_lds16(src, &Xs[buf][split][(wv & 1) * 64]);
    };

    stage(0, 0);
    __syncthreads();
    int cur = 0;
    for (int ks = 0; ks < 32; ++ks) {
        if (ks + 1 < 32) stage(cur ^ 1, (ks + 1) * 32);
        B8 bh, bl;
        {
            int r = rt * 16 + l15;
            bh.u = Xs[cur][0][r * 4 + (lg ^ (r & 3))];
            bl.u = Xs[cur][1][r * 4 + (lg ^ (r & 3))];
        }
#pragma unroll
        for (int mt = 0; mt < 6; ++mt) {
            int c = ch * 192 + cq * 96 + mt * 16 + l15;
            size_t off = (size_t)c * DMODEL + ks * 32 + lg * 8;
            B8 ah, al;
            ah.u = *(const uint4*)(Wth + off);
            al.u = *(const uint4*)(Wtl + off);
            acc[mt] = __builtin_amdgcn_mfma_f32_16x16x32_bf16(
                ah.b, bh.b, acc[mt], 0, 0, 0);
            acc[mt] = __builtin_amdgcn_mfma_f32_16x16x32_bf16(
                ah.b, bl.b, acc[mt], 0, 0, 0);
            acc[mt] = __builtin_amdgcn_mfma_f32_16x16x32_bf16(
                al.b, bh.b, acc[mt], 0, 0, 0);
        }
        __syncthreads();
        cur ^= 1;
    }

    const int r = rb + rt * 16 + l15;
#pragma unroll
    for (int mt = 0; mt < 6; ++mt) {
        int ctile = ch * 192 + cq * 96 + mt * 16;   // multiple of 16, uniform
#pragma unroll
        for (int q = 0; q < 4; ++q) {
            int c = ctile + lg * 4 + q;
            float x = acc[mt][q];
            if (ctile < 128) {          // Q (scaled)
                float v = x * QSCALE;
                __bf16 hb = (__bf16)v;
                Qh[(size_t)r * DHEAD + c] = b2u(hb);
                Ql[(size_t)r * DHEAD + c] = bfbits(v - (float)hb);
            } else if (ctile < 256) {   // K
                __bf16 hb = (__bf16)x;
                Kh[(size_t)r * DHEAD + (c - 128)] = b2u(hb);
                Kl[(size_t)r * DHEAD + (c - 128)] = bfbits(x - (float)hb);
            } else {                    // V -> transposed bf16
                Vt[(size_t)(c - 256) * N_TOK + r] = bfbits(x);
            }
        }
    }
}

// ---------------------------------------------------------------------------
// K1d: fast zero of out.
// ---------------------------------------------------------------------------
__global__ __launch_bounds__(256) void zero_out(float* __restrict__ out) {
    size_t i = ((size_t)blockIdx.x * 256 + threadIdx.x) * 4;
    *(float4*)(out + i) = (float4){0.f, 0.f, 0.f, 0.f};
}

// ---------------------------------------------------------------------------
// K2 (pass 1): online (m,l) with 4x-BATCHED softmax.
// Skeleton = diag1 (proven ~40-60 us): double-buffered Kt, prefetch at loop
// top, ONE syncthreads per K-tile. Softmax runs once per 4 tiles over 64
// accumulated values (8 occurrences instead of 32; same exp count).
// grid (128 row-blocks, CS col-splits), block 256 = 4 waves.
// ---------------------------------------------------------------------------
__global__ __launch_bounds__(256, 2) void attn_p1(
    const u16* __restrict__ Qh, const u16* __restrict__ Ql,
    const u16* __restrict__ Kh, const u16* __restrict__ Kl,
    float* __restrict__ mpart, float* __restrict__ lpart) {
    __shared__ uint4 Kt[2][2][1024];   // [buf][hi/lo][c*16 + swizzled granule]
    const int tid = threadIdx.x;
    const int lane = tid & 63, wv = tid >> 6;
    const int l15 = lane & 15, lg = lane >> 4;
    const int rb = blockIdx.x * 64;
    const int cb0 = blockIdx.y * CCHUNK;
    const int r_glb = rb + wv * 16 + l15;

    B8 qf[2][4];
#pragma unroll
    for (int kd = 0; kd < 4; ++kd) {
        size_t off = (size_t)r_glb * DHEAD + kd * 32 + lg * 8;
        qf[0][kd].u = *(const uint4*)(Qh + off);
        qf[1][kd].u = *(const uint4*)(Ql + off);
    }

    auto stage = [&](int buf, int it) {
        int cb = cb0 + it * 64;
#pragma unroll
        for (int i = 0; i < 4; ++i) {
            int g = i * 256 + wv * 64 + lane;   // granule 0..1023
            int c = g >> 4;
            int gs = g & 15;
            int gd = gs ^ (c & 7);              // inverse swizzle on source
            size_t soff = (size_t)(cb + c) * DHEAD + gd * 8;
            gl_lds16(Kh + soff, &Kt[buf][0][i * 256 + wv * 64]);
            gl_lds16(Kl + soff, &Kt[buf][1][i * 256 + wv * 64]);
        }
    };

    float m = -INFINITY, l = 0.f;
    stage(0, 0);
    __syncthreads();
    int cur = 0;
    for (int ib = 0; ib < NIT / 4; ++ib) {
        f32x4 acc[4][4];   // [tile-in-batch][ct]
#pragma unroll
        for (int t = 0; t < 4; ++t)
#pragma unroll
            for (int ct = 0; ct < 4; ++ct) acc[t][ct] = (f32x4){0.f, 0.f, 0.f, 0.f};
#pragma unroll
        for (int t = 0; t < 4; ++t) {
            int it = ib * 4 + t;
            if (it + 1 < NIT) stage(cur ^ 1, it + 1);
#pragma unroll
            for (int kd = 0; kd < 4; ++kd) {
#pragma unroll
                for (int ct = 0; ct < 4; ++ct) {
                    int cl = ct * 16 + l15;
                    int gs = (kd * 4 + lg) ^ (cl & 7);
                    B8 ahh, alo;
                    ahh.u = Kt[cur][0][cl * 16 + gs];
                    alo.u = Kt[cur][1][cl * 16 + gs];
                    acc[t][ct] = __builtin_amdgcn_mfma_f32_16x16x32_bf16(
                        ahh.b, qf[0][kd].b, acc[t][ct], 0, 0, 0);
                    acc[t][ct] = __builtin_amdgcn_mfma_f32_16x16x32_bf16(
                        ahh.b, qf[1][kd].b, acc[t][ct], 0, 0, 0);
                    acc[t][ct] = __builtin_amdgcn_mfma_f32_16x16x32_bf16(
                        alo.b, qf[0][kd].b, acc[t][ct], 0, 0, 0);
                }
            }
            __syncthreads();
            cur ^= 1;
        }
        // ONE softmax block per 4 tiles: private per-lane (m,l), no DS ops.
        float tm = -INFINITY;
#pragma unroll
        for (int t = 0; t < 4; ++t)
#pragma unroll
            for (int ct = 0; ct < 4; ++ct)
#pragma unroll
                for (int q = 0; q < 4; ++q) tm = fmaxf(tm, acc[t][ct][q]);
        float mn = fmaxf(m, tm);
        float ps = 0.f;
#pragma unroll
        for (int t = 0; t < 4; ++t)
#pragma unroll
            for (int ct = 0; ct < 4; ++ct)
#pragma unroll
                for (int q = 0; q < 4; ++q) ps += __expf(acc[t][ct][q] - mn);
        l = l * __expf(m - mn) + ps;
        m = mn;
    }

    // merge the 4 lane-group partials of this row (2 shfl steps, once)
    float mm = m, ll = l;
#pragma unroll
    for (int off = 16; off < 64; off <<= 1) {
        float mo = __shfl_xor(mm, off);
        float lo_ = __shfl_xor(ll, off);
        float mx = fmaxf(mm, mo);
        ll = ll * __expf(mm - mx) + lo_ * __expf(mo - mx);
        mm = mx;
    }
    if (lg == 0) {
        mpart[blockIdx.y * N_TOK + r_glb] = mm;
        lpart[blockIdx.y * N_TOK + r_glb] = ll;
    }
}

// ---------------------------------------------------------------------------
// K3 (pass 2): normalized P fp32 to attn + bf16 Pt round-trip + fused O=P·V.
// R5 structure (double-buffered Kt, prefetch at top, 2 barriers/iter).
// ---------------------------------------------------------------------------
__global__ __launch_bounds__(256, 2) void attn_p2(
    const u16* __restrict__ Qh, const u16* __restrict__ Ql,
    const u16* __restrict__ Kh, const u16* __restrict__ Kl,
    const float* __restrict__ mfin, const float* __restrict__ linv,
    float* __restrict__ attn, const u16* __restrict__ Vt,
    float* __restrict__ outp) {
    __shared__ uint4 Kt[2][2][1024];   // [buf][hi/lo][c*16 + swizzled granule]
    __shared__ uint4 Pt[512];          // P tile 64r x 64c bf16, swizzled
    const int tid = threadIdx.x;
    const int lane = tid & 63, wv = tid >> 6;
    const int l15 = lane & 15, lg = lane >> 4;
    const int rb = blockIdx.x * 64;
    const int cb0 = blockIdx.y * CCHUNK;
    const int r_loc = wv * 16 + l15;
    const int r_glb = rb + r_loc;

    B8 qf[2][4];
#pragma unroll
    for (int kd = 0; kd < 4; ++kd) {
        size_t off = (size_t)r_glb * DHEAD + kd * 32 + lg * 8;
        qf[0][kd].u = *(const uint4*)(Qh + off);
        qf[1][kd].u = *(const uint4*)(Ql + off);
    }

    float mreg = mfin[r_glb];
    float rinv = linv[r_glb];
    f32x4 accO[8];
#pragma unroll
    for (int dt = 0; dt < 8; ++dt) accO[dt] = (f32x4){0.f, 0.f, 0.f, 0.f};

    auto stage = [&](int buf, int it) {
        int cb = cb0 + it * 64;
#pragma unroll
        for (int i = 0; i < 4; ++i) {
            int g = i * 256 + wv * 64 + lane;
            int c = g >> 4;
            int gs = g & 15;
            int gd = gs ^ (c & 7);
            size_t soff = (size_t)(cb + c) * DHEAD + gd * 8;
            gl_lds16(Kh + soff, &Kt[buf][0][i * 256 + wv * 64]);
            gl_lds16(Kl + soff, &Kt[buf][1][i * 256 + wv * 64]);
        }
    };

    stage(0, 0);
    __syncthreads();
    int cur = 0;
    for (int it = 0; it < NIT; ++it) {
        if (it + 1 < NIT) stage(cur ^ 1, it + 1);
        f32x4 acc[4];
#pragma unroll
        for (int ct = 0; ct < 4; ++ct) acc[ct] = (f32x4){0.f, 0.f, 0.f, 0.f};
#pragma unroll
        for (int kd = 0; kd < 4; ++kd) {
#pragma unroll
            for (int ct = 0; ct < 4; ++ct) {
                int cl = ct * 16 + l15;
                int gs = (kd * 4 + lg) ^ (cl & 7);
                B8 ahh, alo;
                ahh.u = Kt[cur][0][cl * 16 + gs];
                alo.u = Kt[cur][1][cl * 16 + gs];
                acc[ct] = __builtin_amdgcn_mfma_f32_16x16x32_bf16(
                    ahh.b, qf[0][kd].b, acc[ct], 0, 0, 0);
                acc[ct] = __builtin_amdgcn_mfma_f32_16x16x32_bf16(
                    ahh.b, qf[1][kd].b, acc[ct], 0, 0, 0);
                acc[ct] = __builtin_amdgcn_mfma_f32_16x16x32_bf16(
                    alo.b, qf[0][kd].b, acc[ct], 0, 0, 0);
            }
        }
        // normalized P: fp32 to attn + bf16 to Pt (swizzled)
#pragma unroll
        for (int ct = 0; ct < 4; ++ct) {
            float4 p;
            p.x = __expf(acc[ct][0] - mreg) * rinv;
            p.y = __expf(acc[ct][1] - mreg) * rinv;
            p.z = __expf(acc[ct][2] - mreg) * rinv;
            p.w = __expf(acc[ct][3] - mreg) * rinv;
            int c0 = cb0 + it * 64 + ct * 16 + lg * 4;
            *(float4*)&attn[(size_t)r_glb * N_TOK + c0] = p;
            ushort4 pb;
            pb.x = bfbits(p.x); pb.y = bfbits(p.y);
            pb.z = bfbits(p.z); pb.w = bfbits(p.w);
            int hg = (((ct * 2 + (lg >> 1)) ^ (l15 & 7)) << 1) | (lg & 1);
            ((ushort4*)Pt)[r_loc * 16 + hg] = pb;
        }
        __syncthreads();   // Pt visible (+ staged Kt drain)
        // PV: O[16r x 128d] per wave; A from Pt (own rows), B from Vt (L2)
        int cbv = cb0 + it * 64;
#pragma unroll
        for (int kc = 0; kc < 2; ++kc) {
            B8 a;
            a.u = Pt[r_loc * 8 + ((kc * 4 + lg) ^ (l15 & 7))];
#pragma unroll
            for (int dt = 0; dt < 8; ++dt) {
                B8 b;
                b.u = *(const uint4*)(Vt + (size_t)(dt * 16 + l15) * N_TOK +
                                      cbv + kc * 32 + lg * 8);
                accO[dt] = __builtin_amdgcn_mfma_f32_16x16x32_bf16(
                    a.b, b.b, accO[dt], 0, 0, 0);
            }
        }
        __syncthreads();   // protect Pt before next iter overwrite
        cur ^= 1;
    }

#pragma unroll
    for (int dt = 0; dt < 8; ++dt) {
        int d = dt * 16 + l15;
        int r0 = rb + wv * 16 + lg * 4;
#pragma unroll
        for (int q = 0; q < 4; ++q)
            atomicAdd(&outp[(size_t)(r0 + q) * DHEAD + d], accO[dt][q]);
    }
}

// ---------------------------------------------------------------------------
// K2b: merge CS column-split (m,l) partials -> m_final, 1/l
// ---------------------------------------------------------------------------
__global__ __launch_bounds__(256) void merge_kernel(
    const float* __restrict__ mpart, const float* __restrict__ lpart,
    float* __restrict__ mfin, float* __restrict__ linv) {
    int row = blockIdx.x * 256 + threadIdx.x;
    float m = mpart[row];
#pragma unroll
    for (int c = 1; c < CS; ++c) m = fmaxf(m, mpart[c * N_TOK + row]);
    float l = 0.f;
#pragma unroll
    for (int c = 0; c < CS; ++c)
        l += lpart[c * N_TOK + row] * __expf(mpart[c * N_TOK + row] - m);
    mfin[row] = m;
    linv[row] = 1.0f / l;
}

extern "C" void kernel_launch(void* const* d_in, const int* in_sizes, int n_in,
                              void* d_out, int out_size, void* d_ws, size_t ws_size,
                              hipStream_t stream) {
    const float* X  = (const float*)d_in[0];
    const float* Wq = (const float*)d_in[1];
    const float* Wk = (const float*)d_in[2];
    const float* Wv = (const float*)d_in[3];
    float* out  = (float*)d_out;
    float* attn = out + (size_t)NM;
    float* ws = (float*)d_ws;

    u16*  Vt    = (u16*)ws;                       // NM shorts
    float* mpart = ws + NM / 2;                   // CS*N
    float* lpart = mpart + CS * N_TOK;            // CS*N
    float* mfin  = lpart + CS * N_TOK;            // N
    float* linv  = mfin + N_TOK;                  // N
    float* spl   = ws + NM / 2 + 20 * N_TOK;      // splits base (slack-padded)
    u16* Qh = (u16*)spl;                          // NM shorts each
    u16* Ql = Qh + NM;
    u16* Kh = Ql + NM;
    u16* Kl = Kh + NM;
    u16* Xh = Kl + NM;                            // 8M shorts each
    u16* Xl = Xh + (size_t)N_TOK * DMODEL;
    u16* Wth = Xl + (size_t)N_TOK * DMODEL;       // 384*1024 shorts each
    u16* Wtl = Wth + 384 * DMODEL;

    split_x<<<dim3(4096), 256, 0, stream>>>(X, Xh, Xl);
    splitw<<<dim3(1536), 256, 0, stream>>>(Wq, Wk, Wv, Wth, Wtl);
    proj_mfma<<<dim3(256, 2), 256, 0, stream>>>(Xh, Xl, Wth, Wtl,
                                                Qh, Ql, Kh, Kl, Vt);
    zero_out<<<dim3(1024), 256, 0, stream>>>(out);
    attn_p1<<<dim3(128, CS), 256, 0, stream>>>(Qh, Ql, Kh, Kl, mpart, lpart);
    merge_kernel<<<dim3(32), 256, 0, stream>>>(mpart, lpart, mfin, linv);
    attn_p2<<<dim3(128, CS), 256, 0, stream>>>(Qh, Ql, Kh, Kl, mfin, linv,
                                               attn, Vt, out);
}

// Round 10
// 352.781 us; speedup vs baseline: 1.0355x; 1.0355x over previous
//
#include <hip/hip_runtime.h>
#include <math.h>

#define N_TOK 8192
#define DMODEL 1024
#define DHEAD 128
#define NM (N_TOK * DHEAD)       // 1048576
#define CS 4                     // column splits for attention passes
#define NPART (CS * 2)           // (m,l) partial sets: CS x 2 col-halves
#define CCHUNK (N_TOK / CS)      // 2048
#define NIT (CCHUNK / 64)        // 32
#define QSCALE 0.08838834764831845f

typedef __bf16 bf16x8 __attribute__((ext_vector_type(8)));
typedef float f32x4 __attribute__((ext_vector_type(4)));
typedef unsigned short u16;
typedef unsigned int u32;

union B8 { uint4 u; bf16x8 b; };

static __device__ __forceinline__ float4 ld4(const float* p) {
    return *(const float4*)p;
}

static __device__ __forceinline__ void gl_lds16(const void* g, void* l) {
    __builtin_amdgcn_global_load_lds(
        (const __attribute__((address_space(1))) u32*)g,
        (__attribute__((address_space(3))) u32*)l, 16, 0, 0);
}

static __device__ __forceinline__ u16 bfbits(float x) {
    return __builtin_bit_cast(u16, (__bf16)x);
}
static __device__ __forceinline__ u16 b2u(__bf16 h) {
    return __builtin_bit_cast(u16, h);
}

// ---------------------------------------------------------------------------
// K0a: split X fp32 -> Xh, Xl bf16. 8M elements, grid 4096 x 256.
// ---------------------------------------------------------------------------
__global__ __launch_bounds__(256) void split_x(
    const float* __restrict__ X, u16* __restrict__ Xh, u16* __restrict__ Xl) {
    size_t i0 = ((size_t)blockIdx.x * 256 + threadIdx.x) * 8;
    alignas(16) float v[8];
    alignas(16) u16 h[8];
    alignas(16) u16 l[8];
    *(float4*)&v[0] = ld4(X + i0); *(float4*)&v[4] = ld4(X + i0 + 4);
#pragma unroll
    for (int j = 0; j < 8; ++j) {
        __bf16 hb = (__bf16)v[j];
        h[j] = b2u(hb);
        l[j] = bfbits(v[j] - (float)hb);
    }
    *(uint4*)(Xh + i0) = *(uint4*)h;
    *(uint4*)(Xl + i0) = *(uint4*)l;
}

// ---------------------------------------------------------------------------
// K0b: W [1024][128] x3 -> Wt hi/lo [384][1024] (transposed, concat Q|K|V).
// ---------------------------------------------------------------------------
__global__ __launch_bounds__(256) void splitw(
    const float* __restrict__ Wq, const float* __restrict__ Wk,
    const float* __restrict__ Wv, u16* __restrict__ Wth, u16* __restrict__ Wtl) {
    size_t o = (size_t)blockIdx.x * 256 + threadIdx.x;   // 0..393215
    int k = o & 1023, cg = o >> 10;                      // cg 0..383
    int w = cg >> 7, c = cg & 127;
    const float* W = w == 0 ? Wq : (w == 1 ? Wk : Wv);
    float x = W[(size_t)k * 128 + c];
    __bf16 hb = (__bf16)x;
    Wth[o] = b2u(hb);
    Wtl[o] = bfbits(x - (float)hb);
}

// ---------------------------------------------------------------------------
// K1: projections via bf16x3 MFMA, swapped operands (unchanged — fast).
// ---------------------------------------------------------------------------
__global__ __launch_bounds__(256) void proj_mfma(
    const u16* __restrict__ Xh, const u16* __restrict__ Xl,
    const u16* __restrict__ Wth, const u16* __restrict__ Wtl,
    u16* __restrict__ Qh, u16* __restrict__ Ql,
    u16* __restrict__ Kh, u16* __restrict__ Kl, u16* __restrict__ Vt) {
    __shared__ uint4 Xs[2][2][128];   // [buf][hi/lo][r*4 + swizzled granule]
    const int tid = threadIdx.x, lane = tid & 63, wv = tid >> 6;
    const int l15 = lane & 15, lg = lane >> 4;
    const int rb = blockIdx.x * 32;
    const int ch = blockIdx.y;        // c-base = ch*192
    const int rt = wv & 1;            // r-tile (16 rows)
    const int cq = wv >> 1;           // c-quarter (96 cols)

    f32x4 acc[6];
#pragma unroll
    for (int mt = 0; mt < 6; ++mt) acc[mt] = (f32x4){0.f, 0.f, 0.f, 0.f};

    auto stage = [&](int buf, int k0) {
        int split = wv >> 1;
        int idx = (wv & 1) * 64 + lane;     // granule 0..127 within split
        int r = idx >> 2, gs = idx & 3, gd = gs ^ (r & 3);
        const u16* src = (split ? Xl : Xh) +
                         (size_t)(rb + r) * DMODEL + k0 + gd * 8;
        gl_lds16(src, &Xs[buf][split][(wv & 1) * 64]);
    };

    stage(0, 0);
    __syncthreads();
    int cur = 0;
    for (int ks = 0; ks < 32; ++ks) {
        if (ks + 1 < 32) stage(cur ^ 1, (ks + 1) * 32);
        B8 bh, bl;
        {
            int r = rt * 16 + l15;
            bh.u = Xs[cur][0][r * 4 + (lg ^ (r & 3))];
            bl.u = Xs[cur][1][r * 4 + (lg ^ (r & 3))];
        }
#pragma unroll
        for (int mt = 0; mt < 6; ++mt) {
            int c = ch * 192 + cq * 96 + mt * 16 + l15;
            size_t off = (size_t)c * DMODEL + ks * 32 + lg * 8;
            B8 ah, al;
            ah.u = *(const uint4*)(Wth + off);
            al.u = *(const uint4*)(Wtl + off);
            acc[mt] = __builtin_amdgcn_mfma_f32_16x16x32_bf16(
                ah.b, bh.b, acc[mt], 0, 0, 0);
            acc[mt] = __builtin_amdgcn_mfma_f32_16x16x32_bf16(
                ah.b, bl.b, acc[mt], 0, 0, 0);
            acc[mt] = __builtin_amdgcn_mfma_f32_16x16x32_bf16(
                al.b, bh.b, acc[mt], 0, 0, 0);
        }
        __syncthreads();
        cur ^= 1;
    }

    const int r = rb + rt * 16 + l15;
#pragma unroll
    for (int mt = 0; mt < 6; ++mt) {
        int ctile = ch * 192 + cq * 96 + mt * 16;   // multiple of 16, uniform
#pragma unroll
        for (int q = 0; q < 4; ++q) {
            int c = ctile + lg * 4 + q;
            float x = acc[mt][q];
            if (ctile < 128) {          // Q (scaled)
                float v = x * QSCALE;
                __bf16 hb = (__bf16)v;
                Qh[(size_t)r * DHEAD + c] = b2u(hb);
                Ql[(size_t)r * DHEAD + c] = bfbits(v - (float)hb);
            } else if (ctile < 256) {   // K
                __bf16 hb = (__bf16)x;
                Kh[(size_t)r * DHEAD + (c - 128)] = b2u(hb);
                Kl[(size_t)r * DHEAD + (c - 128)] = bfbits(x - (float)hb);
            } else {                    // V -> transposed bf16
                Vt[(size_t)(c - 256) * N_TOK + r] = bfbits(x);
            }
        }
    }
}

// ---------------------------------------------------------------------------
// K1d: fast zero of out.
// ---------------------------------------------------------------------------
__global__ __launch_bounds__(256) void zero_out(float* __restrict__ out) {
    size_t i = ((size_t)blockIdx.x * 256 + threadIdx.x) * 4;
    *(float4*)(out + i) = (float4){0.f, 0.f, 0.f, 0.f};
}

// ---------------------------------------------------------------------------
// K2 (pass 1): R10 repartition — wave owns 32 ROWS x 32 COLS of the 64x64
// tile (2x2 wave grid). qf = 16 frags resident; A-reads halved (16/wave/iter,
// each feeds 6 MFMAs). 4x-batched softmax (R9). Per-row (m,l) partials go to
// NPART = CS x 2 col-half sets.
// ---------------------------------------------------------------------------
__global__ __launch_bounds__(256, 2) void attn_p1(
    const u16* __restrict__ Qh, const u16* __restrict__ Ql,
    const u16* __restrict__ Kh, const u16* __restrict__ Kl,
    float* __restrict__ mpart, float* __restrict__ lpart) {
    __shared__ uint4 Kt[2][2][1024];   // [buf][hi/lo][c*16 + swizzled granule]
    const int tid = threadIdx.x;
    const int lane = tid & 63, wv = tid >> 6;
    const int l15 = lane & 15, lg = lane >> 4;
    const int rb = blockIdx.x * 64;
    const int cb0 = blockIdx.y * CCHUNK;
    const int wv_r = (wv & 1) * 32;     // wave's row-half within tile
    const int wv_c = (wv >> 1) * 32;    // wave's col-half within tile

    // Resident Q B-fragments: [hi/lo][rs][kd]  (16 frags = 64 VGPR)
    B8 qf[2][2][4];
#pragma unroll
    for (int rs = 0; rs < 2; ++rs) {
        int r = rb + wv_r + rs * 16 + l15;
#pragma unroll
        for (int kd = 0; kd < 4; ++kd) {
            size_t off = (size_t)r * DHEAD + kd * 32 + lg * 8;
            qf[0][rs][kd].u = *(const uint4*)(Qh + off);
            qf[1][rs][kd].u = *(const uint4*)(Ql + off);
        }
    }

    auto stage = [&](int buf, int it) {
        int cb = cb0 + it * 64;
#pragma unroll
        for (int i = 0; i < 4; ++i) {
            int g = i * 256 + wv * 64 + lane;   // granule 0..1023
            int c = g >> 4;
            int gs = g & 15;
            int gd = gs ^ (c & 7);              // inverse swizzle on source
            size_t soff = (size_t)(cb + c) * DHEAD + gd * 8;
            gl_lds16(Kh + soff, &Kt[buf][0][i * 256 + wv * 64]);
            gl_lds16(Kl + soff, &Kt[buf][1][i * 256 + wv * 64]);
        }
    };

    float m[2] = {-INFINITY, -INFINITY}, l[2] = {0.f, 0.f};
    stage(0, 0);
    __syncthreads();
    int cur = 0;
    for (int ib = 0; ib < NIT / 4; ++ib) {
        f32x4 acc[4][2][2];   // [tile-in-batch][ct][rs]
#pragma unroll
        for (int t = 0; t < 4; ++t)
#pragma unroll
            for (int ct = 0; ct < 2; ++ct)
#pragma unroll
                for (int rs = 0; rs < 2; ++rs)
                    acc[t][ct][rs] = (f32x4){0.f, 0.f, 0.f, 0.f};
#pragma unroll
        for (int t = 0; t < 4; ++t) {
            int it = ib * 4 + t;
            if (it + 1 < NIT) stage(cur ^ 1, it + 1);
#pragma unroll
            for (int kd = 0; kd < 4; ++kd) {
#pragma unroll
                for (int ct = 0; ct < 2; ++ct) {
                    int cl = wv_c + ct * 16 + l15;
                    int gs = (kd * 4 + lg) ^ (cl & 7);
                    B8 ahh, alo;
                    ahh.u = Kt[cur][0][cl * 16 + gs];
                    alo.u = Kt[cur][1][cl * 16 + gs];
#pragma unroll
                    for (int rs = 0; rs < 2; ++rs) {
                        acc[t][ct][rs] = __builtin_amdgcn_mfma_f32_16x16x32_bf16(
                            ahh.b, qf[0][rs][kd].b, acc[t][ct][rs], 0, 0, 0);
                        acc[t][ct][rs] = __builtin_amdgcn_mfma_f32_16x16x32_bf16(
                            ahh.b, qf[1][rs][kd].b, acc[t][ct][rs], 0, 0, 0);
                        acc[t][ct][rs] = __builtin_amdgcn_mfma_f32_16x16x32_bf16(
                            alo.b, qf[0][rs][kd].b, acc[t][ct][rs], 0, 0, 0);
                    }
                }
            }
            __syncthreads();
            cur ^= 1;
        }
        // ONE softmax block per 4 tiles, per rowset: private (m,l), no DS ops.
#pragma unroll
        for (int rs = 0; rs < 2; ++rs) {
            float tm = -INFINITY;
#pragma unroll
            for (int t = 0; t < 4; ++t)
#pragma unroll
                for (int ct = 0; ct < 2; ++ct)
#pragma unroll
                    for (int q = 0; q < 4; ++q)
                        tm = fmaxf(tm, acc[t][ct][rs][q]);
            float mn = fmaxf(m[rs], tm);
            float ps = 0.f;
#pragma unroll
            for (int t = 0; t < 4; ++t)
#pragma unroll
                for (int ct = 0; ct < 2; ++ct)
#pragma unroll
                    for (int q = 0; q < 4; ++q)
                        ps += __expf(acc[t][ct][rs][q] - mn);
            l[rs] = l[rs] * __expf(m[rs] - mn) + ps;
            m[rs] = mn;
        }
    }

    // merge the 4 lane-group partials (cols within this wave's half), once
#pragma unroll
    for (int rs = 0; rs < 2; ++rs) {
        float mm = m[rs], ll = l[rs];
#pragma unroll
        for (int off = 16; off < 64; off <<= 1) {
            float mo = __shfl_xor(mm, off);
            float lo_ = __shfl_xor(ll, off);
            float mx = fmaxf(mm, mo);
            ll = ll * __expf(mm - mx) + lo_ * __expf(mo - mx);
            mm = mx;
        }
        if (lg == 0) {
            int set = blockIdx.y * 2 + (wv >> 1);   // CS x col-half
            int r = rb + wv_r + rs * 16 + l15;
            mpart[set * N_TOK + r] = mm;
            lpart[set * N_TOK + r] = ll;
        }
    }
}

// ---------------------------------------------------------------------------
// K3 (pass 2): R10 repartition for QK^T; P fp32 to attn + bf16 Pt; PV block
// unchanged from R9 (each wave does 16 rows x 128 d from Pt + L2 Vt).
// ---------------------------------------------------------------------------
__global__ __launch_bounds__(256, 2) void attn_p2(
    const u16* __restrict__ Qh, const u16* __restrict__ Ql,
    const u16* __restrict__ Kh, const u16* __restrict__ Kl,
    const float* __restrict__ mfin, const float* __restrict__ linv,
    float* __restrict__ attn, const u16* __restrict__ Vt,
    float* __restrict__ outp) {
    __shared__ uint4 Kt[2][2][1024];   // [buf][hi/lo][c*16 + swizzled granule]
    __shared__ uint4 Pt[512];          // P tile 64r x 64c bf16, swizzled
    const int tid = threadIdx.x;
    const int lane = tid & 63, wv = tid >> 6;
    const int l15 = lane & 15, lg = lane >> 4;
    const int rb = blockIdx.x * 64;
    const int cb0 = blockIdx.y * CCHUNK;
    const int wv_r = (wv & 1) * 32;
    const int wv_c = (wv >> 1) * 32;
    const int r_pv = wv * 16 + l15;     // PV row ownership (R9 layout)

    B8 qf[2][2][4];
#pragma unroll
    for (int rs = 0; rs < 2; ++rs) {
        int r = rb + wv_r + rs * 16 + l15;
#pragma unroll
        for (int kd = 0; kd < 4; ++kd) {
            size_t off = (size_t)r * DHEAD + kd * 32 + lg * 8;
            qf[0][rs][kd].u = *(const uint4*)(Qh + off);
            qf[1][rs][kd].u = *(const uint4*)(Ql + off);
        }
    }

    float mreg[2], rinv[2];
#pragma unroll
    for (int rs = 0; rs < 2; ++rs) {
        int r = rb + wv_r + rs * 16 + l15;
        mreg[rs] = mfin[r];
        rinv[rs] = linv[r];
    }
    f32x4 accO[8];
#pragma unroll
    for (int dt = 0; dt < 8; ++dt) accO[dt] = (f32x4){0.f, 0.f, 0.f, 0.f};

    auto stage = [&](int buf, int it) {
        int cb = cb0 + it * 64;
#pragma unroll
        for (int i = 0; i < 4; ++i) {
            int g = i * 256 + wv * 64 + lane;
            int c = g >> 4;
            int gs = g & 15;
            int gd = gs ^ (c & 7);
            size_t soff = (size_t)(cb + c) * DHEAD + gd * 8;
            gl_lds16(Kh + soff, &Kt[buf][0][i * 256 + wv * 64]);
            gl_lds16(Kl + soff, &Kt[buf][1][i * 256 + wv * 64]);
        }
    };

    stage(0, 0);
    __syncthreads();
    int cur = 0;
    for (int it = 0; it < NIT; ++it) {
        if (it + 1 < NIT) stage(cur ^ 1, it + 1);
        f32x4 acc[2][2];   // [ct][rs]
#pragma unroll
        for (int ct = 0; ct < 2; ++ct)
#pragma unroll
            for (int rs = 0; rs < 2; ++rs) acc[ct][rs] = (f32x4){0.f, 0.f, 0.f, 0.f};
#pragma unroll
        for (int kd = 0; kd < 4; ++kd) {
#pragma unroll
            for (int ct = 0; ct < 2; ++ct) {
                int cl = wv_c + ct * 16 + l15;
                int gs = (kd * 4 + lg) ^ (cl & 7);
                B8 ahh, alo;
                ahh.u = Kt[cur][0][cl * 16 + gs];
                alo.u = Kt[cur][1][cl * 16 + gs];
#pragma unroll
                for (int rs = 0; rs < 2; ++rs) {
                    acc[ct][rs] = __builtin_amdgcn_mfma_f32_16x16x32_bf16(
                        ahh.b, qf[0][rs][kd].b, acc[ct][rs], 0, 0, 0);
                    acc[ct][rs] = __builtin_amdgcn_mfma_f32_16x16x32_bf16(
                        ahh.b, qf[1][rs][kd].b, acc[ct][rs], 0, 0, 0);
                    acc[ct][rs] = __builtin_amdgcn_mfma_f32_16x16x32_bf16(
                        alo.b, qf[0][rs][kd].b, acc[ct][rs], 0, 0, 0);
                }
            }
        }
        // normalized P: fp32 to attn + bf16 to Pt (swizzled)
#pragma unroll
        for (int ct = 0; ct < 2; ++ct) {
#pragma unroll
            for (int rs = 0; rs < 2; ++rs) {
                float4 p;
                p.x = __expf(acc[ct][rs][0] - mreg[rs]) * rinv[rs];
                p.y = __expf(acc[ct][rs][1] - mreg[rs]) * rinv[rs];
                p.z = __expf(acc[ct][rs][2] - mreg[rs]) * rinv[rs];
                p.w = __expf(acc[ct][rs][3] - mreg[rs]) * rinv[rs];
                int rl = wv_r + rs * 16 + l15;
                int c0 = cb0 + it * 64 + wv_c + ct * 16 + lg * 4;
                *(float4*)&attn[(size_t)(rb + rl) * N_TOK + c0] = p;
                ushort4 pb;
                pb.x = bfbits(p.x); pb.y = bfbits(p.y);
                pb.z = bfbits(p.z); pb.w = bfbits(p.w);
                int g = (wv >> 1) * 4 + ct * 2 + (lg >> 1);
                int hg = (((g ^ (rl & 7)) << 1) | (lg & 1));
                ((ushort4*)Pt)[rl * 16 + hg] = pb;
            }
        }
        __syncthreads();   // Pt visible (+ staged Kt drain)
        // PV: O[16r x 128d] per wave; A from Pt (rows r_pv), B from Vt (L2)
        int cbv = cb0 + it * 64;
#pragma unroll
        for (int kc = 0; kc < 2; ++kc) {
            B8 a;
            a.u = Pt[r_pv * 8 + ((kc * 4 + lg) ^ (l15 & 7))];
#pragma unroll
            for (int dt = 0; dt < 8; ++dt) {
                B8 b;
                b.u = *(const uint4*)(Vt + (size_t)(dt * 16 + l15) * N_TOK +
                                      cbv + kc * 32 + lg * 8);
                accO[dt] = __builtin_amdgcn_mfma_f32_16x16x32_bf16(
                    a.b, b.b, accO[dt], 0, 0, 0);
            }
        }
        __syncthreads();   // protect Pt before next iter overwrite
        cur ^= 1;
    }

#pragma unroll
    for (int dt = 0; dt < 8; ++dt) {
        int d = dt * 16 + l15;
        int r0 = rb + wv * 16 + lg * 4;
#pragma unroll
        for (int q = 0; q < 4; ++q)
            atomicAdd(&outp[(size_t)(r0 + q) * DHEAD + d], accO[dt][q]);
    }
}

// ---------------------------------------------------------------------------
// K2b: merge NPART (m,l) partial sets -> m_final, 1/l
// ---------------------------------------------------------------------------
__global__ __launch_bounds__(256) void merge_kernel(
    const float* __restrict__ mpart, const float* __restrict__ lpart,
    float* __restrict__ mfin, float* __restrict__ linv) {
    int row = blockIdx.x * 256 + threadIdx.x;
    float m = mpart[row];
#pragma unroll
    for (int c = 1; c < NPART; ++c) m = fmaxf(m, mpart[c * N_TOK + row]);
    float l = 0.f;
#pragma unroll
    for (int c = 0; c < NPART; ++c)
        l += lpart[c * N_TOK + row] * __expf(mpart[c * N_TOK + row] - m);
    mfin[row] = m;
    linv[row] = 1.0f / l;
}

extern "C" void kernel_launch(void* const* d_in, const int* in_sizes, int n_in,
                              void* d_out, int out_size, void* d_ws, size_t ws_size,
                              hipStream_t stream) {
    const float* X  = (const float*)d_in[0];
    const float* Wq = (const float*)d_in[1];
    const float* Wk = (const float*)d_in[2];
    const float* Wv = (const float*)d_in[3];
    float* out  = (float*)d_out;
    float* attn = out + (size_t)NM;
    float* ws = (float*)d_ws;

    u16*  Vt    = (u16*)ws;                       // NM shorts
    float* mpart = ws + NM / 2;                   // NPART*N
    float* lpart = mpart + NPART * N_TOK;         // NPART*N
    float* mfin  = lpart + NPART * N_TOK;         // N
    float* linv  = mfin + N_TOK;                  // N
    float* spl   = ws + NM / 2 + 20 * N_TOK;      // splits base (18N used)
    u16* Qh = (u16*)spl;                          // NM shorts each
    u16* Ql = Qh + NM;
    u16* Kh = Ql + NM;
    u16* Kl = Kh + NM;
    u16* Xh = Kl + NM;                            // 8M shorts each
    u16* Xl = Xh + (size_t)N_TOK * DMODEL;
    u16* Wth = Xl + (size_t)N_TOK * DMODEL;       // 384*1024 shorts each
    u16* Wtl = Wth + 384 * DMODEL;

    split_x<<<dim3(4096), 256, 0, stream>>>(X, Xh, Xl);
    splitw<<<dim3(1536), 256, 0, stream>>>(Wq, Wk, Wv, Wth, Wtl);
    proj_mfma<<<dim3(256, 2), 256, 0, stream>>>(Xh, Xl, Wth, Wtl,
                                                Qh, Ql, Kh, Kl, Vt);
    zero_out<<<dim3(1024), 256, 0, stream>>>(out);
    attn_p1<<<dim3(128, CS), 256, 0, stream>>>(Qh, Ql, Kh, Kl, mpart, lpart);
    merge_kernel<<<dim3(32), 256, 0, stream>>>(mpart, lpart, mfin, linv);
    attn_p2<<<dim3(128, CS), 256, 0, stream>>>(Qh, Ql, Kh, Kl, mfin, linv,
                                               attn, Vt, out);
}